// Round 3
// baseline (858.282 us; speedup 1.0000x reference)
//
#include <hip/hip_runtime.h>
#include <hip/hip_bf16.h>
#include <cstdint>

#define NN 40000
#define NE 160000
#define DIN_ 64
#define DD 32
#define EIN_ 16
#define EHD 128
#define NSTEPS 3

typedef __attribute__((ext_vector_type(8))) short short8v;
typedef __attribute__((ext_vector_type(16))) float f32x16;
typedef unsigned int u32;

__device__ __forceinline__ short f2bfs(float f) {
    union { __hip_bfloat16 h; short s; } u;
    u.h = __float2bfloat16(f);
    return u.s;
}
__device__ __forceinline__ float asf(u32 x) {
    union { u32 i; float f; } v; v.i = x; return v.f;
}

// K1: h = relu(bn1(x @ projW + projb))   [NN,64] @ [64,32]
__global__ __launch_bounds__(256) void k_node_proj(
    const float* __restrict__ x, const float* __restrict__ W,
    const float* __restrict__ b, const float* __restrict__ g,
    const float* __restrict__ bb, float* __restrict__ h) {
    __shared__ float Wl[DIN_ * DD];
    int tid = threadIdx.x;
    for (int i = tid; i < DIN_ * DD; i += 256) Wl[i] = W[i];
    __syncthreads();
    int gid = blockIdx.x * 256 + tid;
    int n = gid >> 5, o = gid & 31;
    const float* xr = x + (size_t)n * DIN_;
    float acc = b[o];
#pragma unroll
    for (int k = 0; k < DIN_; ++k) acc = fmaf(xr[k], Wl[k * DD + o], acc);
    float v = acc * (g[o] * rsqrtf(1.0f + 1e-5f)) + bb[o];
    h[gid] = v > 0.f ? v : 0.f;
}

// K2: ehb(bf16) = relu(bn2(edge_attr @ eW1 + eb1))   [NE,16] @ [16,128]
__global__ __launch_bounds__(256) void k_edge_mlp(
    const float* __restrict__ ea, const float* __restrict__ W1,
    const float* __restrict__ b1, const float* __restrict__ g2,
    const float* __restrict__ b2, unsigned short* __restrict__ ehb) {
    __shared__ float Wl[EIN_ * EHD];
    int tid = threadIdx.x;
    for (int i = tid; i < EIN_ * EHD; i += 256) Wl[i] = W1[i];
    __syncthreads();
    int gid = blockIdx.x * 256 + tid;
    int e = gid >> 7, o = gid & 127;
    const float* er = ea + (size_t)e * EIN_;
    float acc = b1[o];
#pragma unroll
    for (int k = 0; k < EIN_; ++k) acc = fmaf(er[k], Wl[k * EHD + o], acc);
    float v = acc * (g2[o] * rsqrtf(1.0f + 1e-5f)) + b2[o];
    ehb[gid] = (unsigned short)f2bfs(v > 0.f ? v : 0.f);
}

// K3: reorder W2 (+virtual eb2 row kk=128) into MFMA B-fragment order, bf16.
// w2f[(kk*2+h)*512 + l*8 + j] = B_h[k16][o], k16=(l>>5)*4+(j&3)+8*(j>>2), o=l&31, i=16h+k16
__global__ __launch_bounds__(256) void k_prep_w2(
    const float* __restrict__ W2, const float* __restrict__ eb2,
    unsigned short* __restrict__ w2f) {
    int idx = blockIdx.x * 256 + threadIdx.x;
    if (idx >= 129 * 1024) return;
    int kk = idx >> 10;
    int r = idx & 1023;
    int h = r >> 9, l = (r >> 3) & 63, j = r & 7;
    int g = l >> 5, o = l & 31;
    int k16 = g * 4 + (j & 3) + 8 * (j >> 2);
    int i = 16 * h + k16;
    float v = (kk < 128) ? W2[(size_t)kk * 1024 + i * 32 + o] : eb2[i * 32 + o];
    w2f[idx] = (unsigned short)f2bfs(v);
}

__global__ __launch_bounds__(256) void k_zero(float* __restrict__ p) {
    int i = blockIdx.x * 256 + threadIdx.x;
    ((float4*)p)[i] = make_float4(0.f, 0.f, 0.f, 0.f);
}

// K4: fused msg + scatter. Per wave: 32 edges x 32 outputs via mfma_f32_32x32x16_bf16.
// msg[e,o] = sum_kk eh[e,kk] * sum_i x[src_e,i] * W2[kk, i*32+o]  (+ eb2 via virtual kk=128)
__global__ __launch_bounds__(256) void k_msg_fused(
    const unsigned short* __restrict__ ehb,   // [E][128] bf16
    const float* __restrict__ hcur,           // [N][32] f32
    const int* __restrict__ ei,               // [2][E]
    const unsigned short* __restrict__ w2f,   // [129][2][64][8] bf16
    float* __restrict__ agg) {                // [N][32] f32
    __shared__ unsigned short w2s[16384];     // 32 KB: 16-kk chunk of w2f
    __shared__ unsigned short ehs[4][32 * 136]; // per-wave eh tile, row stride 272B
    __shared__ int dsts[4][32];
    int tid = threadIdx.x;
    int wv = tid >> 6, l = tid & 63;
    int m = l & 31, hh = l >> 5;              // edge-row / out-col, lane-group
    int e = blockIdx.x * 128 + wv * 32 + m;

    int srcv = ei[e];
    if (hh == 0) dsts[wv][m] = ei[NE + e];

    // gather x row: lane needs i = s*8 + hh*4 + {0..3}, s=0..3
    const float* xrow = hcur + (size_t)srcv * DD;
    float xf[16];
#pragma unroll
    for (int s = 0; s < 4; ++s) {
        float4 q = *(const float4*)(xrow + s * 8 + hh * 4);
        xf[s * 4 + 0] = q.x; xf[s * 4 + 1] = q.y;
        xf[s * 4 + 2] = q.z; xf[s * 4 + 3] = q.w;
    }
    // stage this wave's eh tile (32 edges x 128 bf16) into LDS, 16B segments
    {
        const unsigned short* ehrow = ehb + (size_t)e * 128;
        char* dstrow = (char*)&ehs[wv][0] + m * 272;
#pragma unroll
        for (int j = 0; j < 8; ++j) {
            int seg = j * 2 + hh;
            *(short8v*)(dstrow + seg * 16) = *(const short8v*)(ehrow + seg * 8);
        }
    }

    f32x16 acc;
#pragma unroll
    for (int r = 0; r < 16; ++r) acc[r] = 0.f;

    const char* ehrd = (const char*)&ehs[wv][0] + m * 272;
    for (int c = 0; c < 8; ++c) {
        __syncthreads();   // all waves done reading previous chunk (and eh staged, 1st iter)
        // stage w2 chunk c: 16 kk x 1024 shorts = 32 KB, linear copy by 256 threads
        {
            const short8v* src8 = (const short8v*)(w2f + (size_t)c * 16384);
            short8v* dst8 = (short8v*)w2s;
#pragma unroll
            for (int t = 0; t < 8; ++t) {
                int i8 = t * 256 + tid;
                dst8[i8] = src8[i8];
            }
        }
        __syncthreads();
#pragma unroll
        for (int g2 = 0; g2 < 2; ++g2) {
            // 8 kk worth of eh for this edge-row, one 16B LDS read
            short8v ev = *(const short8v*)(ehrd + (c * 2 + g2) * 16);
            u32 eu[4];
            eu[0] = (u32)(unsigned short)ev[0] | ((u32)(unsigned short)ev[1] << 16);
            eu[1] = (u32)(unsigned short)ev[2] | ((u32)(unsigned short)ev[3] << 16);
            eu[2] = (u32)(unsigned short)ev[4] | ((u32)(unsigned short)ev[5] << 16);
            eu[3] = (u32)(unsigned short)ev[6] | ((u32)(unsigned short)ev[7] << 16);
#pragma unroll
            for (int q = 0; q < 8; ++q) {
                u32 w = eu[q >> 1];
                float ehf = asf((q & 1) ? (w & 0xffff0000u) : (w << 16));
                short8v a0, a1;
#pragma unroll
                for (int j = 0; j < 4; ++j) {
                    a0[j]     = f2bfs(ehf * xf[j]);       // seg0: i = hh*4+j
                    a0[j + 4] = f2bfs(ehf * xf[4 + j]);   // seg1: i = 8+hh*4+j
                    a1[j]     = f2bfs(ehf * xf[8 + j]);   // seg2: i = 16+hh*4+j
                    a1[j + 4] = f2bfs(ehf * xf[12 + j]);  // seg3: i = 24+hh*4+j
                }
                int kkl = g2 * 8 + q;
                const short8v* bb = (const short8v*)w2s + kkl * 128 + l;
                short8v b0 = bb[0];
                short8v b1 = bb[64];
                acc = __builtin_amdgcn_mfma_f32_32x32x16_bf16(a0, b0, acc, 0, 0, 0);
                acc = __builtin_amdgcn_mfma_f32_32x32x16_bf16(a1, b1, acc, 0, 0, 0);
            }
        }
    }
    // virtual kk = 128 (eh == 1): adds sum_i x[src,i]*eb2[i*32+o]
    {
        short8v a0, a1;
#pragma unroll
        for (int j = 0; j < 4; ++j) {
            a0[j]     = f2bfs(xf[j]);
            a0[j + 4] = f2bfs(xf[4 + j]);
            a1[j]     = f2bfs(xf[8 + j]);
            a1[j + 4] = f2bfs(xf[12 + j]);
        }
        const short8v* wf8 = (const short8v*)w2f;
        short8v b0 = wf8[16384 + l];
        short8v b1 = wf8[16448 + l];
        acc = __builtin_amdgcn_mfma_f32_32x32x16_bf16(a0, b0, acc, 0, 0, 0);
        acc = __builtin_amdgcn_mfma_f32_32x32x16_bf16(a1, b1, acc, 0, 0, 0);
    }
    // scatter: reg r -> row m_r = (r&3)+8*(r>>2)+4*hh, col = l&31
#pragma unroll
    for (int r = 0; r < 16; ++r) {
        int mr = (r & 3) + 8 * (r >> 2) + 4 * hh;
        int dv = dsts[wv][mr];
        atomicAdd(&agg[(size_t)dv * DD + m], acc[r]);
    }
}

// K5: conv = agg + h@root + cbias; m = relu(conv); GRU(m, h) -> hout
__global__ __launch_bounds__(256) void k_update(
    const float* __restrict__ hcur, const float* __restrict__ agg,
    const float* __restrict__ root, const float* __restrict__ cbias,
    const float* __restrict__ Wih, const float* __restrict__ Whh,
    const float* __restrict__ bih, const float* __restrict__ bhh,
    float* __restrict__ hout) {
    __shared__ float hs[8][33];
    __shared__ float ms[8][33];
    int tid = threadIdx.x, nl = tid >> 5, o = tid & 31;
    int n = blockIdx.x * 8 + nl;
    float hval = hcur[(size_t)n * DD + o];
    hs[nl][o] = hval;
    __syncthreads();
    float conv = agg[(size_t)n * DD + o] + cbias[o];
#pragma unroll
    for (int i = 0; i < DD; ++i) conv = fmaf(hs[nl][i], root[i * DD + o], conv);
    float m = conv > 0.f ? conv : 0.f;
    ms[nl][o] = m;
    __syncthreads();
    float gir = bih[o], giz = bih[32 + o], gin = bih[64 + o];
    float ghr = bhh[o], ghz = bhh[32 + o], ghn = bhh[64 + o];
#pragma unroll
    for (int i = 0; i < DD; ++i) {
        float mi = ms[nl][i], hi = hs[nl][i];
        gir = fmaf(mi, Wih[o * DD + i], gir);
        giz = fmaf(mi, Wih[(32 + o) * DD + i], giz);
        gin = fmaf(mi, Wih[(64 + o) * DD + i], gin);
        ghr = fmaf(hi, Whh[o * DD + i], ghr);
        ghz = fmaf(hi, Whh[(32 + o) * DD + i], ghz);
        ghn = fmaf(hi, Whh[(64 + o) * DD + i], ghn);
    }
    float r = 1.f / (1.f + expf(-(gir + ghr)));
    float z = 1.f / (1.f + expf(-(giz + ghz)));
    float nt = tanhf(gin + r * ghn);
    hout[(size_t)n * DD + o] = (1.f - z) * nt + z * hval;
}

extern "C" void kernel_launch(void* const* d_in, const int* in_sizes, int n_in,
                              void* d_out, int out_size, void* d_ws, size_t ws_size,
                              hipStream_t stream) {
    const float* x     = (const float*)d_in[0];
    const int*   ei    = (const int*)d_in[1];
    const float* ea    = (const float*)d_in[2];
    const float* projW = (const float*)d_in[3];
    const float* projB = (const float*)d_in[4];
    const float* bn1g  = (const float*)d_in[5];
    const float* bn1b  = (const float*)d_in[6];
    const float* eW1   = (const float*)d_in[7];
    const float* eb1   = (const float*)d_in[8];
    const float* bn2g  = (const float*)d_in[9];
    const float* bn2b  = (const float*)d_in[10];
    const float* eW2   = (const float*)d_in[11];
    const float* eb2   = (const float*)d_in[12];
    const float* root  = (const float*)d_in[13];
    const float* cbias = (const float*)d_in[14];
    const float* Wih   = (const float*)d_in[15];
    const float* Whh   = (const float*)d_in[16];
    const float* bih   = (const float*)d_in[17];
    const float* bhh   = (const float*)d_in[18];

    char* ws = (char*)d_ws;
    unsigned short* ehb = (unsigned short*)(ws + 0);            // 40,960,000 B
    unsigned short* w2f = (unsigned short*)(ws + 41000000UL);   //    264,192 B
    float*          hA  = (float*)(ws + 41600000UL);            //  5,120,000 B
    float*          hB  = (float*)(ws + 46720000UL);            //  5,120,000 B
    float*          agg = (float*)(ws + 51840000UL);            //  5,120,000 B
    // total 56,960,000 B

    k_node_proj<<<(NN * DD) / 256, 256, 0, stream>>>(x, projW, projB, bn1g, bn1b, hA);
    k_edge_mlp<<<(NE * EHD) / 256, 256, 0, stream>>>(ea, eW1, eb1, bn2g, bn2b, ehb);
    k_prep_w2<<<516, 256, 0, stream>>>(eW2, eb2, w2f);

    float* hcur = hA;
    float* hnext = hB;
    for (int s = 0; s < NSTEPS; ++s) {
        k_zero<<<(NN * DD / 4) / 256, 256, 0, stream>>>(agg);
        k_msg_fused<<<NE / 128, 256, 0, stream>>>(ehb, hcur, ei, w2f, agg);
        float* outp = (s == NSTEPS - 1) ? (float*)d_out : hnext;
        k_update<<<NN / 8, 256, 0, stream>>>(hcur, agg, root, cbias, Wih, Whh, bih, bhh, outp);
        hnext = hcur;
        hcur = outp;
    }
}

// Round 7
// 482.125 us; speedup vs baseline: 1.7802x; 1.7802x over previous
//
#include <hip/hip_runtime.h>
#include <hip/hip_bf16.h>
#include <cstdint>

#define NN 40000
#define NE 160000
#define DIN_ 64
#define DD 32
#define EIN_ 16
#define EHD 128
#define NSTEPS 3

typedef __attribute__((ext_vector_type(8))) short short8v;
typedef __attribute__((ext_vector_type(16))) float f32x16;
typedef unsigned int u32;

__device__ __forceinline__ short f2bfs(float f) {
    union { __hip_bfloat16 h; short s; } u;
    u.h = __float2bfloat16(f);
    return u.s;
}
__device__ __forceinline__ float asf(u32 x) {
    union { u32 i; float f; } v; v.i = x; return v.f;
}
__device__ __forceinline__ float sigf(float x) { return 1.f / (1.f + expf(-x)); }

// K1: h = relu(bn1(x @ projW + projb))   [NN,64] @ [64,32]
// lane: og=l&7 (4 outputs), nslot=l>>3 (8 nodes/wave); 32 nodes/block-pass.
__global__ __launch_bounds__(256) void k_node_proj(
    const float* __restrict__ x, const float* __restrict__ W,
    const float* __restrict__ b, const float* __restrict__ g,
    const float* __restrict__ bb, float* __restrict__ h) {
    __shared__ float Wf[DIN_ * DD];        // [k][o] 8 KB
    __shared__ float xsw[4][8][68];        // per-wave x rows, padded
    int tid = threadIdx.x;
    for (int i = tid; i < DIN_ * DD; i += 256) Wf[i] = W[i];
    __syncthreads();
    int wv = tid >> 6, l = tid & 63;
    int ns = l >> 3, og = l & 7;
    float4 g4 = *(const float4*)(g + og * 4);
    float4 b4 = *(const float4*)(b + og * 4);
    float4 bb4 = *(const float4*)(bb + og * 4);
    float sc = rsqrtf(1.0f + 1e-5f);
    float s4[4] = {g4.x * sc, g4.y * sc, g4.z * sc, g4.w * sc};
    float t4[4] = {b4.x * s4[0] + bb4.x, b4.y * s4[1] + bb4.y,
                   b4.z * s4[2] + bb4.z, b4.w * s4[3] + bb4.w};
    for (int n0 = blockIdx.x * 32; n0 < NN; n0 += gridDim.x * 32) {
        // stage 8 node rows (512 floats) per wave, contiguous
        const float* xsrc = x + (size_t)(n0 + wv * 8) * DIN_;
#pragma unroll
        for (int j = 0; j < 8; ++j) xsw[wv][j][l] = xsrc[j * 64 + l];
        float acc[4] = {0.f, 0.f, 0.f, 0.f};
#pragma unroll 16
        for (int k = 0; k < DIN_; ++k) {
            float xk = xsw[wv][ns][k];
            float4 w4 = *(const float4*)&Wf[k * DD + og * 4];
            acc[0] = fmaf(xk, w4.x, acc[0]);
            acc[1] = fmaf(xk, w4.y, acc[1]);
            acc[2] = fmaf(xk, w4.z, acc[2]);
            acc[3] = fmaf(xk, w4.w, acc[3]);
        }
        int n = n0 + wv * 8 + ns;
        float4 o4;
        o4.x = fmaxf(acc[0] * s4[0] + t4[0], 0.f);
        o4.y = fmaxf(acc[1] * s4[1] + t4[1], 0.f);
        o4.z = fmaxf(acc[2] * s4[2] + t4[2], 0.f);
        o4.w = fmaxf(acc[3] * s4[3] + t4[3], 0.f);
        *(float4*)(h + (size_t)n * DD + og * 4) = o4;
    }
}

// K2: ehb(bf16) = relu(bn2(edge_attr @ eW1 + eb1))   [NE,16] @ [16,128]
// lane: og=l&15 (8 outputs), es=l>>4 (4 edges/wave); 16 edges/block-pass.
__global__ __launch_bounds__(256) void k_edge_mlp(
    const float* __restrict__ ea, const float* __restrict__ W1,
    const float* __restrict__ b1, const float* __restrict__ g2,
    const float* __restrict__ b2, unsigned short* __restrict__ ehb) {
    __shared__ float W1s[EIN_ * EHD];      // [k][o] 8 KB
    __shared__ float easw[4][4][17];       // per-wave ea rows, padded
    int tid = threadIdx.x;
    for (int i = tid; i < EIN_ * EHD; i += 256) W1s[i] = W1[i];
    __syncthreads();
    int wv = tid >> 6, l = tid & 63;
    int es = l >> 4, og = l & 15;
    float sc = rsqrtf(1.0f + 1e-5f);
    float s8[8], t8[8];
#pragma unroll
    for (int c = 0; c < 2; ++c) {
        float4 gg = *(const float4*)(g2 + og * 8 + c * 4);
        float4 b14 = *(const float4*)(b1 + og * 8 + c * 4);
        float4 b24 = *(const float4*)(b2 + og * 8 + c * 4);
        s8[c * 4 + 0] = gg.x * sc; s8[c * 4 + 1] = gg.y * sc;
        s8[c * 4 + 2] = gg.z * sc; s8[c * 4 + 3] = gg.w * sc;
        t8[c * 4 + 0] = b14.x * s8[c * 4 + 0] + b24.x;
        t8[c * 4 + 1] = b14.y * s8[c * 4 + 1] + b24.y;
        t8[c * 4 + 2] = b14.z * s8[c * 4 + 2] + b24.z;
        t8[c * 4 + 3] = b14.w * s8[c * 4 + 3] + b24.w;
    }
    for (int e0 = blockIdx.x * 16; e0 < NE; e0 += gridDim.x * 16) {
        easw[wv][l >> 4][l & 15] = ea[(size_t)(e0 + wv * 4) * EIN_ + l];
        float acc[8] = {};
#pragma unroll
        for (int k = 0; k < EIN_; ++k) {
            float a = easw[wv][es][k];
            float4 wa = *(const float4*)&W1s[k * EHD + og * 8];
            float4 wb = *(const float4*)&W1s[k * EHD + og * 8 + 4];
            acc[0] = fmaf(a, wa.x, acc[0]); acc[1] = fmaf(a, wa.y, acc[1]);
            acc[2] = fmaf(a, wa.z, acc[2]); acc[3] = fmaf(a, wa.w, acc[3]);
            acc[4] = fmaf(a, wb.x, acc[4]); acc[5] = fmaf(a, wb.y, acc[5]);
            acc[6] = fmaf(a, wb.z, acc[6]); acc[7] = fmaf(a, wb.w, acc[7]);
        }
        int e = e0 + wv * 4 + es;
        short8v ov;
#pragma unroll
        for (int j = 0; j < 8; ++j)
            ov[j] = f2bfs(fmaxf(acc[j] * s8[j] + t8[j], 0.f));
        *(short8v*)(ehb + (size_t)e * EHD + og * 8) = ov;
    }
}

// K3: reorder W2 (+virtual eb2 row kk=128) into MFMA B-fragment order, bf16.
__global__ __launch_bounds__(256) void k_prep_w2(
    const float* __restrict__ W2, const float* __restrict__ eb2,
    unsigned short* __restrict__ w2f) {
    int idx = blockIdx.x * 256 + threadIdx.x;
    if (idx >= 129 * 1024) return;
    int kk = idx >> 10;
    int r = idx & 1023;
    int h = r >> 9, l = (r >> 3) & 63, j = r & 7;
    int g = l >> 5, o = l & 31;
    int k16 = g * 4 + (j & 3) + 8 * (j >> 2);
    int i = 16 * h + k16;
    float v = (kk < 128) ? W2[(size_t)kk * 1024 + i * 32 + o] : eb2[i * 32 + o];
    w2f[idx] = (unsigned short)f2bfs(v);
}

__global__ __launch_bounds__(256) void k_zero(float* __restrict__ p) {
    int i = blockIdx.x * 256 + threadIdx.x;
    ((float4*)p)[i] = make_float4(0.f, 0.f, 0.f, 0.f);
}

// K4: fused msg + scatter. Per wave: 32 edges x 32 outputs via mfma_f32_32x32x16_bf16.
__global__ __launch_bounds__(256) void k_msg_fused(
    const unsigned short* __restrict__ ehb,   // [E][128] bf16
    const float* __restrict__ hcur,           // [N][32] f32
    const int* __restrict__ ei,               // [2][E]
    const unsigned short* __restrict__ w2f,   // [129][2][64][8] bf16
    float* __restrict__ agg) {                // [N][32] f32
    __shared__ unsigned short w2s[16384];     // 32 KB: 16-kk chunk of w2f
    __shared__ unsigned short ehs[4][32 * 136];
    __shared__ int dsts[4][32];
    int tid = threadIdx.x;
    int wv = tid >> 6, l = tid & 63;
    int m = l & 31, hh = l >> 5;
    int e = blockIdx.x * 128 + wv * 32 + m;

    int srcv = ei[e];
    if (hh == 0) dsts[wv][m] = ei[NE + e];

    const float* xrow = hcur + (size_t)srcv * DD;
    float xf[16];
#pragma unroll
    for (int s = 0; s < 4; ++s) {
        float4 q = *(const float4*)(xrow + s * 8 + hh * 4);
        xf[s * 4 + 0] = q.x; xf[s * 4 + 1] = q.y;
        xf[s * 4 + 2] = q.z; xf[s * 4 + 3] = q.w;
    }
    {
        const unsigned short* ehrow = ehb + (size_t)e * 128;
        char* dstrow = (char*)&ehs[wv][0] + m * 272;
#pragma unroll
        for (int j = 0; j < 8; ++j) {
            int seg = j * 2 + hh;
            *(short8v*)(dstrow + seg * 16) = *(const short8v*)(ehrow + seg * 8);
        }
    }

    f32x16 acc;
#pragma unroll
    for (int r = 0; r < 16; ++r) acc[r] = 0.f;

    const char* ehrd = (const char*)&ehs[wv][0] + m * 272;
    for (int c = 0; c < 8; ++c) {
        __syncthreads();
        {
            const short8v* src8 = (const short8v*)(w2f + (size_t)c * 16384);
            short8v* dst8 = (short8v*)w2s;
#pragma unroll
            for (int t = 0; t < 8; ++t) {
                int i8 = t * 256 + tid;
                dst8[i8] = src8[i8];
            }
        }
        __syncthreads();
#pragma unroll
        for (int g2 = 0; g2 < 2; ++g2) {
            short8v ev = *(const short8v*)(ehrd + (c * 2 + g2) * 16);
            u32 eu[4];
            eu[0] = (u32)(unsigned short)ev[0] | ((u32)(unsigned short)ev[1] << 16);
            eu[1] = (u32)(unsigned short)ev[2] | ((u32)(unsigned short)ev[3] << 16);
            eu[2] = (u32)(unsigned short)ev[4] | ((u32)(unsigned short)ev[5] << 16);
            eu[3] = (u32)(unsigned short)ev[6] | ((u32)(unsigned short)ev[7] << 16);
#pragma unroll
            for (int q = 0; q < 8; ++q) {
                u32 w = eu[q >> 1];
                float ehf = asf((q & 1) ? (w & 0xffff0000u) : (w << 16));
                short8v a0, a1;
#pragma unroll
                for (int j = 0; j < 4; ++j) {
                    a0[j]     = f2bfs(ehf * xf[j]);
                    a0[j + 4] = f2bfs(ehf * xf[4 + j]);
                    a1[j]     = f2bfs(ehf * xf[8 + j]);
                    a1[j + 4] = f2bfs(ehf * xf[12 + j]);
                }
                int kkl = g2 * 8 + q;
                const short8v* bb = (const short8v*)w2s + kkl * 128 + l;
                short8v b0 = bb[0];
                short8v b1 = bb[64];
                acc = __builtin_amdgcn_mfma_f32_32x32x16_bf16(a0, b0, acc, 0, 0, 0);
                acc = __builtin_amdgcn_mfma_f32_32x32x16_bf16(a1, b1, acc, 0, 0, 0);
            }
        }
    }
    {
        short8v a0, a1;
#pragma unroll
        for (int j = 0; j < 4; ++j) {
            a0[j]     = f2bfs(xf[j]);
            a0[j + 4] = f2bfs(xf[4 + j]);
            a1[j]     = f2bfs(xf[8 + j]);
            a1[j + 4] = f2bfs(xf[12 + j]);
        }
        const short8v* wf8 = (const short8v*)w2f;
        short8v b0 = wf8[16384 + l];
        short8v b1 = wf8[16448 + l];
        acc = __builtin_amdgcn_mfma_f32_32x32x16_bf16(a0, b0, acc, 0, 0, 0);
        acc = __builtin_amdgcn_mfma_f32_32x32x16_bf16(a1, b1, acc, 0, 0, 0);
    }
#pragma unroll
    for (int r = 0; r < 16; ++r) {
        int mr = (r & 3) + 8 * (r >> 2) + 4 * hh;
        int dv = dsts[wv][mr];
        atomicAdd(&agg[(size_t)dv * DD + m], acc[r]);
    }
}

// K5: conv/relu + GRU. lane: og=l&7 (4 outputs), ns=l>>3 (8 nodes/wave); 32/block-pass.
// Weights LDS-staged transposed, conflict-free broadcast reads; no syncs in pass loop.
__global__ __launch_bounds__(256) void k_update(
    const float* __restrict__ hcur, const float* __restrict__ agg,
    const float* __restrict__ root, const float* __restrict__ cbias,
    const float* __restrict__ Wih, const float* __restrict__ Whh,
    const float* __restrict__ bih, const float* __restrict__ bhh,
    float* __restrict__ hout) {
    __shared__ float Rl[DD * DD];          // [i][o] 4 KB
    __shared__ float WTih[DD][100];        // [i][go] 12.5 KB
    __shared__ float WThh[DD][100];
    __shared__ float hsw[4][8][36];
    __shared__ float msw[4][8][36];
    int tid = threadIdx.x;
    for (int i = tid; i < DD * DD; i += 256) Rl[i] = root[i];
    for (int idx = tid; idx < 96 * DD; idx += 256) {
        int i = idx & 31, go = idx >> 5;
        WTih[i][go] = Wih[(size_t)go * DD + i];
        WThh[i][go] = Whh[(size_t)go * DD + i];
    }
    __syncthreads();
    int wv = tid >> 6, l = tid & 63;
    int ns = l >> 3, og = l & 7;
    float4 cb4 = *(const float4*)(cbias + og * 4);
    float4 bi4[3], bh4[3];
#pragma unroll
    for (int g = 0; g < 3; ++g) {
        bi4[g] = *(const float4*)(bih + g * 32 + og * 4);
        bh4[g] = *(const float4*)(bhh + g * 32 + og * 4);
    }
    for (int n0 = blockIdx.x * 32; n0 < NN; n0 += gridDim.x * 32) {
        int n = n0 + wv * 8 + ns;
        float4 h4 = *(const float4*)(hcur + (size_t)n * DD + og * 4);
        *(float4*)&hsw[wv][ns][og * 4] = h4;
        float4 a4 = *(const float4*)(agg + (size_t)n * DD + og * 4);
        float cv[4] = {a4.x + cb4.x, a4.y + cb4.y, a4.z + cb4.z, a4.w + cb4.w};
#pragma unroll 8
        for (int i = 0; i < DD; ++i) {
            float hb = hsw[wv][ns][i];
            float4 r4 = *(const float4*)&Rl[i * DD + og * 4];
            cv[0] = fmaf(hb, r4.x, cv[0]); cv[1] = fmaf(hb, r4.y, cv[1]);
            cv[2] = fmaf(hb, r4.z, cv[2]); cv[3] = fmaf(hb, r4.w, cv[3]);
        }
        float4 m4;
        m4.x = fmaxf(cv[0], 0.f); m4.y = fmaxf(cv[1], 0.f);
        m4.z = fmaxf(cv[2], 0.f); m4.w = fmaxf(cv[3], 0.f);
        *(float4*)&msw[wv][ns][og * 4] = m4;
        float gi[3][4], gh[3][4];
#pragma unroll
        for (int g = 0; g < 3; ++g) {
            gi[g][0] = bi4[g].x; gi[g][1] = bi4[g].y; gi[g][2] = bi4[g].z; gi[g][3] = bi4[g].w;
            gh[g][0] = bh4[g].x; gh[g][1] = bh4[g].y; gh[g][2] = bh4[g].z; gh[g][3] = bh4[g].w;
        }
#pragma unroll 4
        for (int i = 0; i < DD; ++i) {
            float mb = msw[wv][ns][i];
            float hb = hsw[wv][ns][i];
#pragma unroll
            for (int g = 0; g < 3; ++g) {
                float4 wi4 = *(const float4*)&WTih[i][g * 32 + og * 4];
                float4 wh4 = *(const float4*)&WThh[i][g * 32 + og * 4];
                gi[g][0] = fmaf(mb, wi4.x, gi[g][0]); gi[g][1] = fmaf(mb, wi4.y, gi[g][1]);
                gi[g][2] = fmaf(mb, wi4.z, gi[g][2]); gi[g][3] = fmaf(mb, wi4.w, gi[g][3]);
                gh[g][0] = fmaf(hb, wh4.x, gh[g][0]); gh[g][1] = fmaf(hb, wh4.y, gh[g][1]);
                gh[g][2] = fmaf(hb, wh4.z, gh[g][2]); gh[g][3] = fmaf(hb, wh4.w, gh[g][3]);
            }
        }
        float hv[4] = {h4.x, h4.y, h4.z, h4.w};
        float4 o4;
        float out[4];
#pragma unroll
        for (int j = 0; j < 4; ++j) {
            float r = sigf(gi[0][j] + gh[0][j]);
            float z = sigf(gi[1][j] + gh[1][j]);
            float nt = tanhf(gi[2][j] + r * gh[2][j]);
            out[j] = (1.f - z) * nt + z * hv[j];
        }
        o4.x = out[0]; o4.y = out[1]; o4.z = out[2]; o4.w = out[3];
        *(float4*)(hout + (size_t)n * DD + og * 4) = o4;
    }
}

extern "C" void kernel_launch(void* const* d_in, const int* in_sizes, int n_in,
                              void* d_out, int out_size, void* d_ws, size_t ws_size,
                              hipStream_t stream) {
    const float* x     = (const float*)d_in[0];
    const int*   ei    = (const int*)d_in[1];
    const float* ea    = (const float*)d_in[2];
    const float* projW = (const float*)d_in[3];
    const float* projB = (const float*)d_in[4];
    const float* bn1g  = (const float*)d_in[5];
    const float* bn1b  = (const float*)d_in[6];
    const float* eW1   = (const float*)d_in[7];
    const float* eb1   = (const float*)d_in[8];
    const float* bn2g  = (const float*)d_in[9];
    const float* bn2b  = (const float*)d_in[10];
    const float* eW2   = (const float*)d_in[11];
    const float* eb2   = (const float*)d_in[12];
    const float* root  = (const float*)d_in[13];
    const float* cbias = (const float*)d_in[14];
    const float* Wih   = (const float*)d_in[15];
    const float* Whh   = (const float*)d_in[16];
    const float* bih   = (const float*)d_in[17];
    const float* bhh   = (const float*)d_in[18];

    char* ws = (char*)d_ws;
    unsigned short* ehb = (unsigned short*)(ws + 0);            // 40,960,000 B
    unsigned short* w2f = (unsigned short*)(ws + 41000000UL);   //    264,192 B
    float*          hA  = (float*)(ws + 41600000UL);            //  5,120,000 B
    float*          hB  = (float*)(ws + 46720000UL);            //  5,120,000 B
    float*          agg = (float*)(ws + 51840000UL);            //  5,120,000 B

    k_node_proj<<<625, 256, 0, stream>>>(x, projW, projB, bn1g, bn1b, hA);
    k_edge_mlp<<<625, 256, 0, stream>>>(ea, eW1, eb1, bn2g, bn2b, ehb);
    k_prep_w2<<<516, 256, 0, stream>>>(eW2, eb2, w2f);

    float* hcur = hA;
    float* hnext = hB;
    for (int s = 0; s < NSTEPS; ++s) {
        k_zero<<<(NN * DD / 4) / 256, 256, 0, stream>>>(agg);
        k_msg_fused<<<NE / 128, 256, 0, stream>>>(ehb, hcur, ei, w2f, agg);
        float* outp = (s == NSTEPS - 1) ? (float*)d_out : hnext;
        k_update<<<625, 256, 0, stream>>>(hcur, agg, root, cbias, Wih, Whh, bih, bhh, outp);
        hnext = hcur;
        hcur = outp;
    }
}

// Round 8
// 447.261 us; speedup vs baseline: 1.9190x; 1.0779x over previous
//
#include <hip/hip_runtime.h>
#include <hip/hip_bf16.h>
#include <cstdint>

#define NN 40000
#define NE 160000
#define DIN_ 64
#define DD 32
#define EIN_ 16
#define EHD 128
#define NSTEPS 3

typedef __attribute__((ext_vector_type(8))) short short8v;
typedef __attribute__((ext_vector_type(16))) float f32x16;
typedef unsigned int u32;

__device__ __forceinline__ short f2bfs(float f) {
    union { __hip_bfloat16 h; short s; } u;
    u.h = __float2bfloat16(f);
    return u.s;
}
__device__ __forceinline__ float sigf(float x) { return 1.f / (1.f + expf(-x)); }

// K1: h = relu(bn1(x @ projW + projb))   [NN,64] @ [64,32]
__global__ __launch_bounds__(256) void k_node_proj(
    const float* __restrict__ x, const float* __restrict__ W,
    const float* __restrict__ b, const float* __restrict__ g,
    const float* __restrict__ bb, float* __restrict__ h) {
    __shared__ float Wf[DIN_ * DD];
    __shared__ float xsw[4][8][68];
    int tid = threadIdx.x;
    for (int i = tid; i < DIN_ * DD; i += 256) Wf[i] = W[i];
    __syncthreads();
    int wv = tid >> 6, l = tid & 63;
    int ns = l >> 3, og = l & 7;
    float4 g4 = *(const float4*)(g + og * 4);
    float4 b4 = *(const float4*)(b + og * 4);
    float4 bb4 = *(const float4*)(bb + og * 4);
    float sc = rsqrtf(1.0f + 1e-5f);
    float s4[4] = {g4.x * sc, g4.y * sc, g4.z * sc, g4.w * sc};
    float t4[4] = {b4.x * s4[0] + bb4.x, b4.y * s4[1] + bb4.y,
                   b4.z * s4[2] + bb4.z, b4.w * s4[3] + bb4.w};
    for (int n0 = blockIdx.x * 32; n0 < NN; n0 += gridDim.x * 32) {
        const float* xsrc = x + (size_t)(n0 + wv * 8) * DIN_;
#pragma unroll
        for (int j = 0; j < 8; ++j) xsw[wv][j][l] = xsrc[j * 64 + l];
        float acc[4] = {0.f, 0.f, 0.f, 0.f};
#pragma unroll 16
        for (int k = 0; k < DIN_; ++k) {
            float xk = xsw[wv][ns][k];
            float4 w4 = *(const float4*)&Wf[k * DD + og * 4];
            acc[0] = fmaf(xk, w4.x, acc[0]);
            acc[1] = fmaf(xk, w4.y, acc[1]);
            acc[2] = fmaf(xk, w4.z, acc[2]);
            acc[3] = fmaf(xk, w4.w, acc[3]);
        }
        int n = n0 + wv * 8 + ns;
        float4 o4;
        o4.x = fmaxf(acc[0] * s4[0] + t4[0], 0.f);
        o4.y = fmaxf(acc[1] * s4[1] + t4[1], 0.f);
        o4.z = fmaxf(acc[2] * s4[2] + t4[2], 0.f);
        o4.w = fmaxf(acc[3] * s4[3] + t4[3], 0.f);
        *(float4*)(h + (size_t)n * DD + og * 4) = o4;
    }
}

// K2: ehb(bf16) = relu(bn2(edge_attr @ eW1 + eb1))   [NE,16] @ [16,128]
__global__ __launch_bounds__(256) void k_edge_mlp(
    const float* __restrict__ ea, const float* __restrict__ W1,
    const float* __restrict__ b1, const float* __restrict__ g2,
    const float* __restrict__ b2, unsigned short* __restrict__ ehb) {
    __shared__ float W1s[EIN_ * EHD];
    __shared__ float easw[4][4][17];
    int tid = threadIdx.x;
    for (int i = tid; i < EIN_ * EHD; i += 256) W1s[i] = W1[i];
    __syncthreads();
    int wv = tid >> 6, l = tid & 63;
    int es = l >> 4, og = l & 15;
    float sc = rsqrtf(1.0f + 1e-5f);
    float s8[8], t8[8];
#pragma unroll
    for (int c = 0; c < 2; ++c) {
        float4 gg = *(const float4*)(g2 + og * 8 + c * 4);
        float4 b14 = *(const float4*)(b1 + og * 8 + c * 4);
        float4 b24 = *(const float4*)(b2 + og * 8 + c * 4);
        s8[c * 4 + 0] = gg.x * sc; s8[c * 4 + 1] = gg.y * sc;
        s8[c * 4 + 2] = gg.z * sc; s8[c * 4 + 3] = gg.w * sc;
        t8[c * 4 + 0] = b14.x * s8[c * 4 + 0] + b24.x;
        t8[c * 4 + 1] = b14.y * s8[c * 4 + 1] + b24.y;
        t8[c * 4 + 2] = b14.z * s8[c * 4 + 2] + b24.z;
        t8[c * 4 + 3] = b14.w * s8[c * 4 + 3] + b24.w;
    }
    for (int e0 = blockIdx.x * 16; e0 < NE; e0 += gridDim.x * 16) {
        easw[wv][l >> 4][l & 15] = ea[(size_t)(e0 + wv * 4) * EIN_ + l];
        float acc[8] = {};
#pragma unroll
        for (int k = 0; k < EIN_; ++k) {
            float a = easw[wv][es][k];
            float4 wa = *(const float4*)&W1s[k * EHD + og * 8];
            float4 wb = *(const float4*)&W1s[k * EHD + og * 8 + 4];
            acc[0] = fmaf(a, wa.x, acc[0]); acc[1] = fmaf(a, wa.y, acc[1]);
            acc[2] = fmaf(a, wa.z, acc[2]); acc[3] = fmaf(a, wa.w, acc[3]);
            acc[4] = fmaf(a, wb.x, acc[4]); acc[5] = fmaf(a, wb.y, acc[5]);
            acc[6] = fmaf(a, wb.z, acc[6]); acc[7] = fmaf(a, wb.w, acc[7]);
        }
        int e = e0 + wv * 4 + es;
        short8v ov;
#pragma unroll
        for (int j = 0; j < 8; ++j)
            ov[j] = f2bfs(fmaxf(acc[j] * s8[j] + t8[j], 0.f));
        *(short8v*)(ehb + (size_t)e * EHD + og * 8) = ov;
    }
}

// K3 v2: W2 -> B-fragments for the H-GEMM (contraction over kk, K=128).
// For ct=0..31 (input dim i), slice s=0..7 (16 kk each):
//   w2f[(ct*8+s)*512 + l*8 + j] = bf16(W2[kk=s*16+k16(l,j)][ct*32 + (l&31)])
// Bias frags (K=32 contraction over i) at elem offset 131072:
//   w2f[131072 + h*512 + l*8 + j] = bf16(eb2[(16h + k16(l,j))*32 + (l&31)])
// with k16(l,j) = (l>>5)*4 + (j&3) + 8*(j>>2).
__global__ __launch_bounds__(256) void k_prep_w2(
    const float* __restrict__ W2, const float* __restrict__ eb2,
    unsigned short* __restrict__ w2f) {
    int idx = blockIdx.x * 256 + threadIdx.x;
    if (idx >= 132096) return;
    float v;
    if (idx < 131072) {
        int ct = idx >> 12;
        int s = (idx >> 9) & 7;
        int l = (idx >> 3) & 63;
        int j = idx & 7;
        int k16 = (l >> 5) * 4 + (j & 3) + 8 * (j >> 2);
        int kk = s * 16 + k16;
        v = W2[(size_t)kk * 1024 + ct * 32 + (l & 31)];
    } else {
        int r = idx - 131072;
        int h = r >> 9;
        int l = (r >> 3) & 63;
        int j = r & 7;
        int k16 = (l >> 5) * 4 + (j & 3) + 8 * (j >> 2);
        v = eb2[(16 * h + k16) * 32 + (l & 31)];
    }
    w2f[idx] = (unsigned short)f2bfs(v);
}

__global__ __launch_bounds__(256) void k_zero(float* __restrict__ p) {
    int i = blockIdx.x * 256 + threadIdx.x;
    ((float4*)p)[i] = make_float4(0.f, 0.f, 0.f, 0.f);
}

// K4 v2: msg[e,o] = sum_i x[e,i] * H[e,i,o],  H[:,i,:] = EH(32x128,bf16) @ W2_i(128x32,bf16)
// Per wave: 32 edges. A-frags (eh) loaded once from global (8x short8v, no cvt VALU).
// Per ct: 8 chained MFMAs build C_ct; macc[r] += x[m_r,ct]*C_ct[r] with broadcast LDS x-reads.
// Bias: 2 MFMAs, A = bf16(x) frags, B = eb2 frags. ct processed in pairs for MFMA ILP.
__global__ __launch_bounds__(256) void k_msg_fused(
    const unsigned short* __restrict__ ehb,   // [E][128] bf16
    const float* __restrict__ hcur,           // [N][32] f32
    const int* __restrict__ ei,               // [2][E]
    const unsigned short* __restrict__ w2f,   // fragment layout (see k_prep_w2)
    float* __restrict__ agg) {                // [N][32] f32
    __shared__ unsigned short w2s[16384];     // 32 KB: 4-ct chunk of B-frags
    __shared__ float xts[4][32][33];          // per-wave x transposed: [i][edge]
    __shared__ int dsts[4][32];
    int tid = threadIdx.x;
    int wv = tid >> 6, l = tid & 63;
    int m = l & 31, hh = l >> 5;
    int e = blockIdx.x * 128 + wv * 32 + m;

    int srcv = ei[e];
    if (hh == 0) dsts[wv][m] = ei[NE + e];

    // gather x row: lane holds x[src, i] for i = s*8 + hh*4 + {0..3}, s=0..3
    const float* xrow = hcur + (size_t)srcv * DD;
    float xf[16];
#pragma unroll
    for (int s = 0; s < 4; ++s) {
        float4 q = *(const float4*)(xrow + s * 8 + hh * 4);
        xf[s * 4 + 0] = q.x; xf[s * 4 + 1] = q.y;
        xf[s * 4 + 2] = q.z; xf[s * 4 + 3] = q.w;
    }
    // transpose x into LDS: xts[wv][i][edge]
#pragma unroll
    for (int s = 0; s < 4; ++s)
#pragma unroll
        for (int j = 0; j < 4; ++j)
            xts[wv][s * 8 + hh * 4 + j][m] = xf[s * 4 + j];

    // A-fragments (eh) straight from global, no conversion:
    // af[s] elem j = ehb[e][s*16 + 4hh + (j&3) + 8*(j>>2)]
    short8v af[8];
    {
        const unsigned short* ehrow = ehb + (size_t)e * EHD;
#pragma unroll
        for (int s = 0; s < 8; ++s) {
            union { uint2 u[2]; short8v v; } cc;
            cc.u[0] = *(const uint2*)(ehrow + s * 16 + hh * 4);
            cc.u[1] = *(const uint2*)(ehrow + s * 16 + 8 + hh * 4);
            af[s] = cc.v;
        }
    }

    // bias: macc = x @ eb2 via 2 MFMAs (A = bf16(x), old verified frag layout)
    f32x16 macc;
#pragma unroll
    for (int r = 0; r < 16; ++r) macc[r] = 0.f;
    {
        short8v xa0, xa1;
#pragma unroll
        for (int j = 0; j < 8; ++j) { xa0[j] = f2bfs(xf[j]); xa1[j] = f2bfs(xf[8 + j]); }
        const short8v* wb = (const short8v*)w2f + 16384;
        short8v b0 = wb[l];
        short8v b1 = wb[64 + l];
        macc = __builtin_amdgcn_mfma_f32_32x32x16_bf16(xa0, b0, macc, 0, 0, 0);
        macc = __builtin_amdgcn_mfma_f32_32x32x16_bf16(xa1, b1, macc, 0, 0, 0);
    }

    const short8v* w2s8 = (const short8v*)w2s;
    for (int c = 0; c < 8; ++c) {
        __syncthreads();   // previous chunk fully consumed (and xts ready on c==0)
        {
            const short8v* src8 = (const short8v*)w2f + (size_t)c * 2048;
            short8v* dst8 = (short8v*)w2s;
#pragma unroll
            for (int t = 0; t < 8; ++t) {
                int i8 = t * 256 + tid;
                dst8[i8] = src8[i8];
            }
        }
        __syncthreads();
#pragma unroll
        for (int p = 0; p < 2; ++p) {   // two ct-pairs per chunk
            f32x16 C0, C1;
#pragma unroll
            for (int r = 0; r < 16; ++r) { C0[r] = 0.f; C1[r] = 0.f; }
#pragma unroll
            for (int s = 0; s < 8; ++s) {
                short8v b0 = w2s8[((p * 2 + 0) * 8 + s) * 64 + l];
                short8v b1 = w2s8[((p * 2 + 1) * 8 + s) * 64 + l];
                C0 = __builtin_amdgcn_mfma_f32_32x32x16_bf16(af[s], b0, C0, 0, 0, 0);
                C1 = __builtin_amdgcn_mfma_f32_32x32x16_bf16(af[s], b1, C1, 0, 0, 0);
            }
            int ct0 = c * 4 + p * 2;
            float4 xq0[4], xq1[4];
#pragma unroll
            for (int g = 0; g < 4; ++g) {
                xq0[g] = *(const float4*)&xts[wv][ct0][g * 8 + hh * 4];
                xq1[g] = *(const float4*)&xts[wv][ct0 + 1][g * 8 + hh * 4];
            }
            // C row for reg r is m_r = (r&3) + 8*(r>>2) + 4hh; xq[g=r>>2] covers m = 8g+4hh+{0..3}
#pragma unroll
            for (int r = 0; r < 16; ++r) {
                float xv0 = ((const float*)&xq0[r >> 2])[r & 3];
                float xv1 = ((const float*)&xq1[r >> 2])[r & 3];
                macc[r] = fmaf(xv0, C0[r], macc[r]);
                macc[r] = fmaf(xv1, C1[r], macc[r]);
            }
        }
    }
    // scatter: reg r -> row m_r = (r&3)+8*(r>>2)+4*hh, col = m
#pragma unroll
    for (int r = 0; r < 16; ++r) {
        int mr = (r & 3) + 8 * (r >> 2) + 4 * hh;
        int dv = dsts[wv][mr];
        atomicAdd(&agg[(size_t)dv * DD + m], macc[r]);
    }
}

// K5: conv/relu + GRU. Weights LDS-staged transposed; 32 nodes/block-pass.
__global__ __launch_bounds__(256) void k_update(
    const float* __restrict__ hcur, const float* __restrict__ agg,
    const float* __restrict__ root, const float* __restrict__ cbias,
    const float* __restrict__ Wih, const float* __restrict__ Whh,
    const float* __restrict__ bih, const float* __restrict__ bhh,
    float* __restrict__ hout) {
    __shared__ float Rl[DD * DD];
    __shared__ float WTih[DD][100];
    __shared__ float WThh[DD][100];
    __shared__ float hsw[4][8][36];
    __shared__ float msw[4][8][36];
    int tid = threadIdx.x;
    for (int i = tid; i < DD * DD; i += 256) Rl[i] = root[i];
    for (int idx = tid; idx < 96 * DD; idx += 256) {
        int i = idx & 31, go = idx >> 5;
        WTih[i][go] = Wih[(size_t)go * DD + i];
        WThh[i][go] = Whh[(size_t)go * DD + i];
    }
    __syncthreads();
    int wv = tid >> 6, l = tid & 63;
    int ns = l >> 3, og = l & 7;
    float4 cb4 = *(const float4*)(cbias + og * 4);
    float4 bi4[3], bh4[3];
#pragma unroll
    for (int g = 0; g < 3; ++g) {
        bi4[g] = *(const float4*)(bih + g * 32 + og * 4);
        bh4[g] = *(const float4*)(bhh + g * 32 + og * 4);
    }
    for (int n0 = blockIdx.x * 32; n0 < NN; n0 += gridDim.x * 32) {
        int n = n0 + wv * 8 + ns;
        float4 h4 = *(const float4*)(hcur + (size_t)n * DD + og * 4);
        *(float4*)&hsw[wv][ns][og * 4] = h4;
        float4 a4 = *(const float4*)(agg + (size_t)n * DD + og * 4);
        float cv[4] = {a4.x + cb4.x, a4.y + cb4.y, a4.z + cb4.z, a4.w + cb4.w};
#pragma unroll 8
        for (int i = 0; i < DD; ++i) {
            float hb = hsw[wv][ns][i];
            float4 r4 = *(const float4*)&Rl[i * DD + og * 4];
            cv[0] = fmaf(hb, r4.x, cv[0]); cv[1] = fmaf(hb, r4.y, cv[1]);
            cv[2] = fmaf(hb, r4.z, cv[2]); cv[3] = fmaf(hb, r4.w, cv[3]);
        }
        float4 m4;
        m4.x = fmaxf(cv[0], 0.f); m4.y = fmaxf(cv[1], 0.f);
        m4.z = fmaxf(cv[2], 0.f); m4.w = fmaxf(cv[3], 0.f);
        *(float4*)&msw[wv][ns][og * 4] = m4;
        float gi[3][4], gh[3][4];
#pragma unroll
        for (int g = 0; g < 3; ++g) {
            gi[g][0] = bi4[g].x; gi[g][1] = bi4[g].y; gi[g][2] = bi4[g].z; gi[g][3] = bi4[g].w;
            gh[g][0] = bh4[g].x; gh[g][1] = bh4[g].y; gh[g][2] = bh4[g].z; gh[g][3] = bh4[g].w;
        }
#pragma unroll 4
        for (int i = 0; i < DD; ++i) {
            float mb = msw[wv][ns][i];
            float hb = hsw[wv][ns][i];
#pragma unroll
            for (int g = 0; g < 3; ++g) {
                float4 wi4 = *(const float4*)&WTih[i][g * 32 + og * 4];
                float4 wh4 = *(const float4*)&WThh[i][g * 32 + og * 4];
                gi[g][0] = fmaf(mb, wi4.x, gi[g][0]); gi[g][1] = fmaf(mb, wi4.y, gi[g][1]);
                gi[g][2] = fmaf(mb, wi4.z, gi[g][2]); gi[g][3] = fmaf(mb, wi4.w, gi[g][3]);
                gh[g][0] = fmaf(hb, wh4.x, gh[g][0]); gh[g][1] = fmaf(hb, wh4.y, gh[g][1]);
                gh[g][2] = fmaf(hb, wh4.z, gh[g][2]); gh[g][3] = fmaf(hb, wh4.w, gh[g][3]);
            }
        }
        float hv[4] = {h4.x, h4.y, h4.z, h4.w};
        float4 o4;
        float out[4];
#pragma unroll
        for (int j = 0; j < 4; ++j) {
            float r = sigf(gi[0][j] + gh[0][j]);
            float z = sigf(gi[1][j] + gh[1][j]);
            float nt = tanhf(gi[2][j] + r * gh[2][j]);
            out[j] = (1.f - z) * nt + z * hv[j];
        }
        o4.x = out[0]; o4.y = out[1]; o4.z = out[2]; o4.w = out[3];
        *(float4*)(hout + (size_t)n * DD + og * 4) = o4;
    }
}

extern "C" void kernel_launch(void* const* d_in, const int* in_sizes, int n_in,
                              void* d_out, int out_size, void* d_ws, size_t ws_size,
                              hipStream_t stream) {
    const float* x     = (const float*)d_in[0];
    const int*   ei    = (const int*)d_in[1];
    const float* ea    = (const float*)d_in[2];
    const float* projW = (const float*)d_in[3];
    const float* projB = (const float*)d_in[4];
    const float* bn1g  = (const float*)d_in[5];
    const float* bn1b  = (const float*)d_in[6];
    const float* eW1   = (const float*)d_in[7];
    const float* eb1   = (const float*)d_in[8];
    const float* bn2g  = (const float*)d_in[9];
    const float* bn2b  = (const float*)d_in[10];
    const float* eW2   = (const float*)d_in[11];
    const float* eb2   = (const float*)d_in[12];
    const float* root  = (const float*)d_in[13];
    const float* cbias = (const float*)d_in[14];
    const float* Wih   = (const float*)d_in[15];
    const float* Whh   = (const float*)d_in[16];
    const float* bih   = (const float*)d_in[17];
    const float* bhh   = (const float*)d_in[18];

    char* ws = (char*)d_ws;
    unsigned short* ehb = (unsigned short*)(ws + 0);            // 40,960,000 B
    unsigned short* w2f = (unsigned short*)(ws + 41000000UL);   //    264,192 B
    float*          hA  = (float*)(ws + 41600000UL);            //  5,120,000 B
    float*          hB  = (float*)(ws + 46720000UL);            //  5,120,000 B
    float*          agg = (float*)(ws + 51840000UL);            //  5,120,000 B

    k_node_proj<<<625, 256, 0, stream>>>(x, projW, projB, bn1g, bn1b, hA);
    k_edge_mlp<<<625, 256, 0, stream>>>(ea, eW1, eb1, bn2g, bn2b, ehb);
    k_prep_w2<<<516, 256, 0, stream>>>(eW2, eb2, w2f);

    float* hcur = hA;
    float* hnext = hB;
    for (int s = 0; s < NSTEPS; ++s) {
        k_zero<<<(NN * DD / 4) / 256, 256, 0, stream>>>(agg);
        k_msg_fused<<<NE / 128, 256, 0, stream>>>(ehb, hcur, ei, w2f, agg);
        float* outp = (s == NSTEPS - 1) ? (float*)d_out : hnext;
        k_update<<<625, 256, 0, stream>>>(hcur, agg, root, cbias, Wih, Whh, bih, bhh, outp);
        hnext = hcur;
        hcur = outp;
    }
}